// Round 3
// baseline (512.455 us; speedup 1.0000x reference)
//
#include <hip/hip_runtime.h>

// out[n,o] = sum_i x[n,i]*W[o,i] + b[o]
// x: 524288x128 fp32, W: 128x128 fp32 row-major [o][i], b: 128, out: 524288x128 fp32.
//
// Memory-bound (~537 MB mandatory HBM traffic -> ~85us floor at 6.3 TB/s).
// fp16 MFMA 16x16x32, fp32 accumulate. A-operand = W, B-operand = x so the
// C/D layout (row=o=quad*4+reg, col=n=lane&15) gives float4 stores along o.
// Each wave owns a 32-wide o-strip (2 MFMA o-tiles -> only 32 VGPRs of W
// fragments, 8 acc regs). Block of 4 waves covers all 128 o for a 16-row
// n-chunk; register double-buffer prefetches the next chunk's x.

typedef __fp16   fp16x2   __attribute__((ext_vector_type(2)));  // cvt_pkrtz result
typedef _Float16 half8_t  __attribute__((ext_vector_type(8)));  // MFMA A/B operand
typedef float    float4_t __attribute__((ext_vector_type(4)));

constexpr int BATCH = 524288;
constexpr int K = 128;
constexpr int N = 128;
constexpr int ROWS_PER_CHUNK = 16;
constexpr int NCHUNK = BATCH / ROWS_PER_CHUNK;   // 32768
constexpr int GRID = 4096;
constexpr int CHUNKS_PER_BLOCK = NCHUNK / GRID;  // 8 contiguous chunks per block

__device__ __forceinline__ half8_t pack8(float4_t a, float4_t b) {
    union { half8_t v; fp16x2 h[4]; } u;
    u.h[0] = __builtin_amdgcn_cvt_pkrtz(a.x, a.y);
    u.h[1] = __builtin_amdgcn_cvt_pkrtz(a.z, a.w);
    u.h[2] = __builtin_amdgcn_cvt_pkrtz(b.x, b.y);
    u.h[3] = __builtin_amdgcn_cvt_pkrtz(b.z, b.w);
    return u.v;
}

__global__ __launch_bounds__(256, 3)
void linear_mfma_v3(const float* __restrict__ x,
                    const float* __restrict__ W,
                    const float* __restrict__ bias,
                    float* __restrict__ out)
{
    const int lane = threadIdx.x & 63;
    const int wave = threadIdx.x >> 6;
    const int l15  = lane & 15;
    const int quad = lane >> 4;
    const int obase = wave * 32;          // this wave's 32-wide o-strip

    // ---- W fragments (A-operand): A[m=l15][k=quad*8+j], tile t covers
    // o = obase + t*16 + m. 2 tiles x 4 k-chunks x 16B = 32 VGPRs. ----
    half8_t wf[2][4];
#pragma unroll
    for (int t = 0; t < 2; ++t) {
        const float* wp = W + (size_t)(obase + t * 16 + l15) * K + quad * 8;
#pragma unroll
        for (int c = 0; c < 4; ++c) {
            float4_t w0 = *(const float4_t*)(wp + c * 32);
            float4_t w1 = *(const float4_t*)(wp + c * 32 + 4);
            wf[t][c] = pack8(w0, w1);
        }
    }

    // bias per lane: C/D row (=o) = quad*4 + r  ->  float4 along r
    float4_t bv[2];
#pragma unroll
    for (int t = 0; t < 2; ++t)
#pragma unroll
        for (int r = 0; r < 4; ++r)
            bv[t][r] = bias[obase + t * 16 + quad * 4 + r];

    const int chunk0 = blockIdx.x * CHUNKS_PER_BLOCK;
    // B-operand (x): B[k=quad*8+j][n=l15] -> lane reads x[n0+l15][quad*8 + c*32 .. +8]
    const float* xbase = x + (size_t)(chunk0 * ROWS_PER_CHUNK + l15) * K + quad * 8;

    // prologue: load chunk 0 (8 x float4 = 32 VGPRs)
    float4_t xa[8];
#pragma unroll
    for (int c = 0; c < 4; ++c) {
        xa[2 * c]     = *(const float4_t*)(xbase + c * 32);
        xa[2 * c + 1] = *(const float4_t*)(xbase + c * 32 + 4);
    }

    for (int it = 0; it < CHUNKS_PER_BLOCK; ++it) {
        // prefetch next chunk (last iter re-loads current: L1 hit, keeps code branch-free)
        const int nx = (it + 1 < CHUNKS_PER_BLOCK) ? it + 1 : it;
        const float* xp = xbase + (size_t)nx * ROWS_PER_CHUNK * K;
        float4_t xn[8];
#pragma unroll
        for (int c = 0; c < 4; ++c) {
            xn[2 * c]     = *(const float4_t*)(xp + c * 32);
            xn[2 * c + 1] = *(const float4_t*)(xp + c * 32 + 4);
        }

        // compute current chunk
        float4_t acc0 = (float4_t)0.0f, acc1 = (float4_t)0.0f;
#pragma unroll
        for (int c = 0; c < 4; ++c) {
            half8_t bx = pack8(xa[2 * c], xa[2 * c + 1]);
            acc0 = __builtin_amdgcn_mfma_f32_16x16x32_f16(wf[0][c], bx, acc0, 0, 0, 0);
            acc1 = __builtin_amdgcn_mfma_f32_16x16x32_f16(wf[1][c], bx, acc1, 0, 0, 0);
        }

        // store: lane holds out[n = n0+l15][o = obase + t*16 + quad*4 .. +4)
        float* op = out + (size_t)((chunk0 + it) * ROWS_PER_CHUNK + l15) * N
                        + obase + quad * 4;
        __builtin_nontemporal_store(acc0 + bv[0], (float4_t*)op);
        __builtin_nontemporal_store(acc1 + bv[1], (float4_t*)(op + 16));

#pragma unroll
        for (int c = 0; c < 8; ++c) xa[c] = xn[c];
    }
}

extern "C" void kernel_launch(void* const* d_in, const int* in_sizes, int n_in,
                              void* d_out, int out_size, void* d_ws, size_t ws_size,
                              hipStream_t stream) {
    const float* x = (const float*)d_in[0];
    const float* W = (const float*)d_in[1];
    const float* b = (const float*)d_in[2];
    float* out = (float*)d_out;
    linear_mfma_v3<<<GRID, 256, 0, stream>>>(x, W, b, out);
}